// Round 13
// baseline (165.759 us; speedup 1.0000x reference)
//
#include <hip/hip_runtime.h>

// ---- constants (problem sizes fixed by reference) ----
#define T_SEQ 2048
#define HID   2048
#define HQ    16
#define HKV   8
#define DH    128
#define NQKV  4096   // HQ*DH + 2*HKV*DH

#define QSCALE (0.08838834764831845f * 1.4426950408889634f)  // 1/sqrt(128) * log2(e)

typedef __attribute__((ext_vector_type(8))) __bf16 bf16x8;
typedef __attribute__((ext_vector_type(4))) float f32x4;
typedef __attribute__((ext_vector_type(8))) unsigned short ushort8;

__device__ __forceinline__ unsigned short f2bfc(float f) {
  return __builtin_bit_cast(unsigned short, (__bf16)f);
}

__device__ __forceinline__ void gload_lds16(const void* g, void* l) {
  __builtin_amdgcn_global_load_lds((const __attribute__((address_space(1))) void*)g,
                                   (__attribute__((address_space(3))) void*)l, 16, 0, 0);
}

// ---- merged pre-pass (NO atomics): blocks 0..511 = gate + fp32->bf16 hidden cvt;
//      blocks 512..3583 = weight transposes (fp32 [R][C] -> bf16 [C][R]) ----
__global__ __launch_bounds__(256) void k_pre(const float* __restrict__ hid,
                                             const float* __restrict__ gw,
                                             const float* __restrict__ gb,
                                             const float* __restrict__ Wq,
                                             const float* __restrict__ Wk,
                                             const float* __restrict__ Wv,
                                             const float* __restrict__ Wo,
                                             float* __restrict__ lb,
                                             unsigned short* __restrict__ hbf,
                                             unsigned short* __restrict__ BtQKV,
                                             unsigned short* __restrict__ WoT) {
  __shared__ float tile[64][65];
  if (blockIdx.x < 512) {
    const int t = blockIdx.x * 4 + (threadIdx.x >> 6);
    const int lane = threadIdx.x & 63;
    float acc[8];
#pragma unroll
    for (int h = 0; h < 8; h++) acc[h] = 0.f;
    const float* hrow = hid + (size_t)t * HID;
    unsigned short* brow = hbf + (size_t)t * HID;
    for (int i = lane * 4; i < HID; i += 256) {
      const float4 hv = *(const float4*)(hrow + i);
      unsigned long long pk = (unsigned long long)f2bfc(hv.x)
                            | ((unsigned long long)f2bfc(hv.y) << 16)
                            | ((unsigned long long)f2bfc(hv.z) << 32)
                            | ((unsigned long long)f2bfc(hv.w) << 48);
      *(unsigned long long*)(brow + i) = pk;
      const float ve[4] = {hv.x, hv.y, hv.z, hv.w};
#pragma unroll
      for (int e = 0; e < 4; e++) {
        const float v = ve[e];
        const float4 a = *(const float4*)(gw + (size_t)(i + e) * 8);
        const float4 b = *(const float4*)(gw + (size_t)(i + e) * 8 + 4);
        acc[0] += v * a.x; acc[1] += v * a.y; acc[2] += v * a.z; acc[3] += v * a.w;
        acc[4] += v * b.x; acc[5] += v * b.y; acc[6] += v * b.z; acc[7] += v * b.w;
      }
    }
#pragma unroll
    for (int off = 32; off >= 1; off >>= 1)
#pragma unroll
      for (int h = 0; h < 8; h++) acc[h] += __shfl_xor(acc[h], off);
    if (lane == 0) {
#pragma unroll
      for (int h = 0; h < 8; h++) {
        const float x = acc[h] + gb[h];
        const float beta = 1.f / (1.f + __expf(-x));
        lb[(size_t)h * T_SEQ + t] = log2f(fmaxf(beta, 1e-8f));   // log2 domain
      }
    }
    return;
  }
  int b = blockIdx.x - 512;
  const float* in; unsigned short* out; int ldin;
  if (b < 1024)      { in = Wq; out = BtQKV;                          ldin = 2048; }
  else if (b < 1536) { b -= 1024; in = Wk; out = BtQKV + (size_t)2048 * 2048; ldin = 1024; }
  else if (b < 2048) { b -= 1536; in = Wv; out = BtQKV + (size_t)3072 * 2048; ldin = 1024; }
  else               { b -= 2048; in = Wo; out = WoT;                 ldin = 2048; }
  const int ldout = 2048;
  const int r0 = (b & 31) * 64, c0 = (b >> 5) * 64;
  const int tid = threadIdx.x;
  {
    const int row = tid >> 4;
    const int cf  = (tid & 15) * 4;
#pragma unroll
    for (int k = 0; k < 4; k++) {
      const int r = row + k * 16;
      float4 v = *(const float4*)(in + (size_t)(r0 + r) * ldin + c0 + cf);
      tile[r][cf + 0] = v.x; tile[r][cf + 1] = v.y;
      tile[r][cf + 2] = v.z; tile[r][cf + 3] = v.w;
    }
  }
  __syncthreads();
  {
    const int c    = tid >> 3;
    const int rseg = (tid & 7) * 8;
#pragma unroll
    for (int k = 0; k < 2; k++) {
      const int cc = c + k * 32;
      ushort8 ov;
#pragma unroll
      for (int e = 0; e < 8; e++) ov[e] = f2bfc(tile[rseg + e][cc]);
      *(ushort8*)(out + (size_t)(c0 + cc) * ldout + r0 + rseg) = ov;
    }
  }
}

// ---- fused QKV GEMM + per-head RMSNorm + RoPE + Q-scale + V-transpose ----
__global__ __launch_bounds__(256) void k_qkv(const unsigned short* __restrict__ A,
                                             const unsigned short* __restrict__ Bt,
                                             const float* __restrict__ qw,
                                             const float* __restrict__ kw,
                                             const float* __restrict__ cosT,
                                             const float* __restrict__ sinT,
                                             unsigned short* __restrict__ Qb,
                                             unsigned short* __restrict__ Kb,
                                             unsigned short* __restrict__ Vt) {
  __shared__ __align__(16) char smem[67072];
  unsigned short* lA = (unsigned short*)smem;                 // 2 bufs x 8192 shorts
  unsigned short* lB = (unsigned short*)(smem + 32768);       // 2 bufs x 8192 shorts
  float* yLds  = (float*)smem;                                // [128][129] (union)
  float* ssLds = (float*)(smem + 66048);                      // [2][128]

  const int K = HID;
  const int tid = threadIdx.x;
  const int wid = tid >> 6, lane = tid & 63;
  const int lr = lane & 15, lg = lane >> 4;
  const int wr = wid >> 1, wc = wid & 1;

  int wg = blockIdx.x;
  wg = (wg & 7) * 64 + (wg >> 3);          // XCD-chunked bijective swizzle (grid 512)
  const int mt = wg & 15, nt0 = wg >> 4;   // nt0 0..31: Q heads 0..15, K 16..23, V 24..31
  const size_t tile_m = (size_t)mt * 128, tile_n = (size_t)nt0 * 128;

  f32x4 acc[4][4];
#pragma unroll
  for (int i = 0; i < 4; i++)
#pragma unroll
    for (int j = 0; j < 4; j++) acc[i][j] = (f32x4){0.f, 0.f, 0.f, 0.f};

  const int srow = lane >> 3, schunk = lane & 7;
  auto stage = [&](int kb, int buf) {
#pragma unroll
    for (int i = 0; i < 4; i++) {
      const int rbase = wid * 32 + i * 8;
      const int r = rbase + srow;
      const int cs = (schunk ^ (r & 7)) * 8;
      gload_lds16(A  + (tile_m + r) * (size_t)K + kb + cs, lA + buf * 8192 + rbase * 64);
      gload_lds16(Bt + (tile_n + r) * (size_t)K + kb + cs, lB + buf * 8192 + rbase * 64);
    }
  };

  const int nk = K / 64;
  stage(0, 0);
  int cur = 0;
  for (int t = 0; t < nk; ++t) {
    if (t + 1 < nk) {
      stage((t + 1) * 64, cur ^ 1);
      asm volatile("s_waitcnt vmcnt(8)" ::: "memory");  // tile t landed; t+1 in flight
    } else {
      asm volatile("s_waitcnt vmcnt(0)" ::: "memory");
    }
    __builtin_amdgcn_s_barrier();
#pragma unroll
    for (int kk = 0; kk < 2; kk++) {
      bf16x8 af[4], bfr[4];
#pragma unroll
      for (int mi = 0; mi < 4; mi++) {
        const int rr = wr * 64 + mi * 16 + lr;
        af[mi] = *(const bf16x8*)&lA[cur * 8192 + rr * 64 + (((kk * 4 + lg) ^ (rr & 7)) * 8)];
      }
#pragma unroll
      for (int ni = 0; ni < 4; ni++) {
        const int rr = wc * 64 + ni * 16 + lr;
        bfr[ni] = *(const bf16x8*)&lB[cur * 8192 + rr * 64 + (((kk * 4 + lg) ^ (rr & 7)) * 8)];
      }
#pragma unroll
      for (int mi = 0; mi < 4; mi++)
#pragma unroll
        for (int ni = 0; ni < 4; ni++)
          acc[mi][ni] = __builtin_amdgcn_mfma_f32_16x16x32_bf16(af[mi], bfr[ni], acc[mi][ni], 0, 0, 0);
    }
    __builtin_amdgcn_s_barrier();
    cur ^= 1;
  }

  // ================= fused epilogue =================
  const int isV = nt0 >= 24;
  const int isQ = nt0 < 16;
  float rinv[4][4];
  float wv[4];
  if (!isV) {
#pragma unroll
    for (int mi = 0; mi < 4; mi++)
#pragma unroll
      for (int r = 0; r < 4; r++) {
        float s = 0.f;
#pragma unroll
        for (int ni = 0; ni < 4; ni++) { const float v = acc[mi][ni][r]; s += v * v; }
#pragma unroll
        for (int off = 8; off >= 1; off >>= 1) s += __shfl_xor(s, off);
        if (lr == 0) ssLds[wc * 128 + wr * 64 + mi * 16 + lg * 4 + r] = s;
      }
    __syncthreads();
#pragma unroll
    for (int mi = 0; mi < 4; mi++)
#pragma unroll
      for (int r = 0; r < 4; r++) {
        const int row = wr * 64 + mi * 16 + lg * 4 + r;
        rinv[mi][r] = rsqrtf((ssLds[row] + ssLds[128 + row]) * (1.f / 128.f) + 1e-6f);
      }
    const float* w = isQ ? qw : kw;
#pragma unroll
    for (int ni = 0; ni < 4; ni++) wv[ni] = w[wc * 64 + ni * 16 + lr];
  }
#pragma unroll
  for (int mi = 0; mi < 4; mi++)
#pragma unroll
    for (int ni = 0; ni < 4; ni++)
#pragma unroll
      for (int r = 0; r < 4; r++) {
        const int row = wr * 64 + mi * 16 + lg * 4 + r;
        const int col = wc * 64 + ni * 16 + lr;
        float y = acc[mi][ni][r];
        if (!isV) y *= rinv[mi][r] * wv[ni];
        yLds[row * 129 + col] = y;
      }
  __syncthreads();
  if (!isV) {
    const float scale = isQ ? QSCALE : 1.f;
    const int row = tid >> 1, half = tid & 1;
    const int t = (int)tile_m + row;
    const float sgn = half ? 1.f : -1.f;
    const float* cro = cosT + (size_t)t * DH + half * 64;
    const float* sro = sinT + (size_t)t * DH + half * 64;
    const float* own = yLds + row * 129 + half * 64;
    const float* par = yLds + row * 129 + (half ^ 1) * 64;
    unsigned short* op = isQ ? (Qb + (size_t)t * 2048 + nt0 * DH + half * 64)
                             : (Kb + (size_t)t * 1024 + (nt0 - 16) * DH + half * 64);
#pragma unroll
    for (int c = 0; c < 64; c += 8) {
      ushort8 ov;
#pragma unroll
      for (int e = 0; e < 8; e++)
        ov[e] = f2bfc((own[c + e] * cro[c + e] + sgn * par[c + e] * sro[c + e]) * scale);
      *(ushort8*)(op + c) = ov;
    }
  } else {
    const int d = tid >> 1, thalf = tid & 1;
    const int vh = nt0 - 24;
    unsigned short* op = Vt + (size_t)(vh * DH + d) * T_SEQ + tile_m + thalf * 64;
#pragma unroll
    for (int s = 0; s < 64; s += 8) {
      ushort8 ov;
#pragma unroll
      for (int e = 0; e < 8; e++) ov[e] = f2bfc(yLds[(thalf * 64 + s + e) * 129 + d]);
      *(ushort8*)(op + s) = ov;
    }
  }
}

// ---- out-proj GEMM: 64x128 tiles, grid 512 (2 blocks/CU), depth-2 pipeline
//      (3 LDS bufs, counted vmcnt never drained in-loop), plain fp32 stores ----
__global__ __launch_bounds__(256) void k_gemm_o(const unsigned short* __restrict__ A,
                                                const unsigned short* __restrict__ Bt,
                                                float* __restrict__ C) {
  __shared__ unsigned short lA[3][64 * 64];    // 24 KB
  __shared__ unsigned short lB[3][128 * 64];   // 48 KB (72 KB total; 2 blocks/CU)
  const int K = 2048, N = 2048;
  const int tid = threadIdx.x;
  const int wid = tid >> 6, lane = tid & 63;
  const int lr = lane & 15, lg = lane >> 4;
  const int wr = wid >> 1, wc = wid & 1;

  int wg = blockIdx.x;
  wg = (wg & 7) * 64 + (wg >> 3);          // XCD-chunked bijective swizzle (grid 512)
  const size_t tile_m = (size_t)(wg & 31) * 64;    // 32 M-tiles
  const size_t tile_n = (size_t)(wg >> 5) * 128;   // 16 N-tiles

  f32x4 acc[2][4];
#pragma unroll
  for (int i = 0; i < 2; i++)
#pragma unroll
    for (int j = 0; j < 4; j++) acc[i][j] = (f32x4){0.f, 0.f, 0.f, 0.f};

  const int srow = (lane >> 3);
  const int schunk = lane & 7;
  auto stage = [&](int kb, int buf) {
#pragma unroll
    for (int i = 0; i < 2; i++) {            // A: 64 rows
      const int rbase = wid * 16 + i * 8;
      const int r = rbase + srow;
      const int cs = (schunk ^ (r & 7)) * 8;
      gload_lds16(A + (tile_m + r) * (size_t)K + kb + cs, &lA[buf][rbase * 64]);
    }
#pragma unroll
    for (int i = 0; i < 4; i++) {            // B: 128 rows
      const int rbase = wid * 32 + i * 8;
      const int r = rbase + srow;
      const int cs = (schunk ^ (r & 7)) * 8;
      gload_lds16(Bt + (tile_n + r) * (size_t)K + kb + cs, &lB[buf][rbase * 64]);
    }
  };

  const int nk = K / 64;   // 32
  stage(0, 0);
  stage(64, 1);
  int cur = 0;
  for (int t = 0; t < nk; ++t) {
    if (t + 2 < nk) {
      int nb = cur + 2; if (nb >= 3) nb -= 3;
      stage((t + 2) * 64, nb);
      asm volatile("s_waitcnt vmcnt(12)" ::: "memory");  // tile t landed; t+1,t+2 in flight
    } else if (t + 2 == nk) {
      asm volatile("s_waitcnt vmcnt(6)" ::: "memory");   // tile t landed; t+1 in flight
    } else {
      asm volatile("s_waitcnt vmcnt(0)" ::: "memory");
    }
    __builtin_amdgcn_s_barrier();
#pragma unroll
    for (int kk = 0; kk < 2; kk++) {
      bf16x8 af[2], bfr[4];
#pragma unroll
      for (int mi = 0; mi < 2; mi++) {
        const int rr = wr * 32 + mi * 16 + lr;
        af[mi] = *(const bf16x8*)&lA[cur][rr * 64 + (((kk * 4 + lg) ^ (rr & 7)) * 8)];
      }
#pragma unroll
      for (int ni = 0; ni < 4; ni++) {
        const int rr = wc * 64 + ni * 16 + lr;
        bfr[ni] = *(const bf16x8*)&lB[cur][rr * 64 + (((kk * 4 + lg) ^ (rr & 7)) * 8)];
      }
#pragma unroll
      for (int mi = 0; mi < 2; mi++)
#pragma unroll
        for (int ni = 0; ni < 4; ni++)
          acc[mi][ni] = __builtin_amdgcn_mfma_f32_16x16x32_bf16(af[mi], bfr[ni], acc[mi][ni], 0, 0, 0);
    }
    __builtin_amdgcn_s_barrier();   // all waves done with cur before it is restaged
    cur = (cur + 1 == 3) ? 0 : cur + 1;
  }
#pragma unroll
  for (int mi = 0; mi < 2; mi++)
#pragma unroll
    for (int ni = 0; ni < 4; ni++)
#pragma unroll
      for (int r = 0; r < 4; r++) {
        const size_t idx = (tile_m + wr * 32 + mi * 16 + lg * 4 + r) * (size_t)N +
                           tile_n + wc * 64 + ni * 16 + lr;
        C[idx] = acc[mi][ni][r];
      }
}

// ---- flash attention: reverse iteration, fixed-max exp2 softmax, rigorous early exit;
//      K staged to LDS (dbuf); V read DIRECT from L2 into registers (T14) ----
__global__ __launch_bounds__(256, 2) void k_attn(const unsigned short* __restrict__ Q,
                                                 const unsigned short* __restrict__ Kb,
                                                 const unsigned short* __restrict__ Vt,
                                                 const float* __restrict__ lb,
                                                 unsigned short* __restrict__ O) {
  const int tid = threadIdx.x;
  const int wid = tid >> 6, lane = tid & 63;
  const int lr = lane & 15, lg = lane >> 4;
  const int u = blockIdx.x;
  const int h = u & 15;
  const int qp = (u >> 4) & 15;
  const int qblk = (u >> 8) ? (31 - qp) : qp;   // complementary-pair balance
  const int kvh = h >> 1;
  const int qb = qblk * 64 + wid * 16;

  __shared__ __align__(16) unsigned short lK[2][64 * 128];   // 32 KB (no V staging)
  __shared__ __align__(16) unsigned short plds[4][16 * 72];
  __shared__ int exitflag[4];
  __shared__ float sred[4];

  const float* lbh = lb + (size_t)kvh * T_SEQ;
  const unsigned short* Kh = Kb + kvh * DH;
  const unsigned short* Vh = Vt + (size_t)kvh * DH * T_SEQ;
  unsigned short* myp = plds[wid];

  bf16x8 qf[4];
  {
    const unsigned short* Qp = Q + (size_t)(qb + lr) * 2048 + h * DH + lg * 8;
#pragma unroll
    for (int kc = 0; kc < 4; kc++) qf[kc] = *(const bf16x8*)(Qp + kc * 32);
  }

  f32x4 o[8];
#pragma unroll
  for (int nc = 0; nc < 8; nc++) o[nc] = (f32x4){0.f, 0.f, 0.f, 0.f};
  float rs[4] = {0.f, 0.f, 0.f, 0.f};

  const int ir[4] = {qb + lg * 4, qb + lg * 4 + 1, qb + lg * 4 + 2, qb + lg * 4 + 3};
  const float fi[4] = {(float)ir[0], (float)ir[1], (float)ir[2], (float)ir[3]};

  auto stage = [&](int kb, int buf) {
#pragma unroll
    for (int q = 0; q < 4; q++) {
      const int t = wid * 4 + q;
      const int r = 4 * t + (lane >> 4);
      const int j = (lane & 15) ^ (r & 7);
      gload_lds16(Kh + (size_t)(kb + r) * 1024 + j * 8, &lK[buf][t * 512]);
    }
  };

  const int nt = qblk + 1;
  int cur = 0;
  float lbj[4], lbn[4];
  {
    const int kb0 = (nt - 1) * 64;
    stage(kb0, 0);
#pragma unroll
    for (int nf = 0; nf < 4; nf++) lbj[nf] = lbh[kb0 + nf * 16 + lr];
  }
  // inline per-head lbmax
  {
    float v = -1e30f;
    for (int i = tid; i < T_SEQ; i += 256) v = fmaxf(v, lbh[i]);
#pragma unroll
    for (int off = 32; off >= 1; off >>= 1) v = fmaxf(v, __shfl_xor(v, off));
    if (lane == 0) sred[wid] = v;
  }
  asm volatile("s_waitcnt vmcnt(0)" ::: "memory");
  __syncthreads();
  const float lbmx = fmaxf(fmaxf(sred[0], sred[1]), fmaxf(sred[2], sred[3]));

  for (int kt = nt - 1; kt >= 0; --kt) {
    const int kb = kt * 64;
    if (kt > 0) {
      stage(kb - 64, cur ^ 1);
#pragma unroll
      for (int nf = 0; nf < 4; nf++) lbn[nf] = lbh[kb - 64 + nf * 16 + lr];
    }
    // ---- V fragments direct from global (L2-hot); issued early, consumed in PV ----
    bf16x8 vreg[16];
#pragma unroll
    for (int nc = 0; nc < 8; nc++) {
      const unsigned short* vp = Vh + (size_t)(nc * 16 + lr) * T_SEQ + kb + lg * 8;
      vreg[nc * 2]     = *(const bf16x8*)vp;
      vreg[nc * 2 + 1] = *(const bf16x8*)(vp + 32);
    }
    // ---- QK^T from lK[cur] ----
    f32x4 sfr[4];
    __builtin_amdgcn_s_setprio(1);
#pragma unroll
    for (int nf = 0; nf < 4; nf++) {
      const int rr = nf * 16 + lr;
      const unsigned short* kbase = &lK[cur][rr * 128];
      f32x4 a = (f32x4){0.f, 0.f, 0.f, 0.f};
#pragma unroll
      for (int kc = 0; kc < 4; kc++) {
        const bf16x8 kf = *(const bf16x8*)&kbase[((kc * 4 + lg) ^ (rr & 7)) * 8];
        a = __builtin_amdgcn_mfma_f32_16x16x32_bf16(qf[kc], kf, a, 0, 0, 0);
      }
      sfr[nf] = a;
    }
    __builtin_amdgcn_s_setprio(0);
    const int last = (kt == nt - 1);
#pragma unroll
    for (int nf = 0; nf < 4; nf++) {
      const int j = kb + nf * 16 + lr;
      const float fj = (float)j;
#pragma unroll
      for (int r = 0; r < 4; r++) {
        float sv = sfr[nf][r] + lbj[nf] * (fi[r] - fj);
        if (last) sv = (j <= ir[r]) ? sv : -1e30f;
        const float p = __builtin_amdgcn_exp2f(sv);
        sfr[nf][r] = p;
        rs[r] += p;
      }
    }
#pragma unroll
    for (int nf = 0; nf < 4; nf++)
#pragma unroll
      for (int r = 0; r < 4; r++)
        myp[(lg * 4 + r) * 72 + nf * 16 + lr] = f2bfc(sfr[nf][r]);
    const bf16x8 pa0 = *(const bf16x8*)&myp[lr * 72 + lg * 8];
    const bf16x8 pa1 = *(const bf16x8*)&myp[lr * 72 + 32 + lg * 8];
    __builtin_amdgcn_s_setprio(1);
#pragma unroll
    for (int nc = 0; nc < 8; nc++) {
      o[nc] = __builtin_amdgcn_mfma_f32_16x16x32_bf16(pa0, vreg[nc * 2], o[nc], 0, 0, 0);
      o[nc] = __builtin_amdgcn_mfma_f32_16x16x32_bf16(pa1, vreg[nc * 2 + 1], o[nc], 0, 0, 0);
    }
    __builtin_amdgcn_s_setprio(0);
    // rigorous early exit: tail(row i) <= 2048*2^(16.5+lbmx*(i-kb+1)) < 2^-10 * lsum
    const int dotest = ((kt & 1) == 0) && (kt > 0);
    if (dotest) {
      float t0 = rs[0], t1 = rs[1], t2 = rs[2], t3 = rs[3];
#pragma unroll
      for (int off = 8; off >= 1; off >>= 1) {
        t0 += __shfl_xor(t0, off); t1 += __shfl_xor(t1, off);
        t2 += __shfl_xor(t2, off); t3 += __shfl_xor(t3, off);
      }
      const float fkb = (float)kb;
      int ok = (__builtin_amdgcn_exp2f(37.5f + lbmx * (fi[0] - fkb + 1.f)) < t0) &
               (__builtin_amdgcn_exp2f(37.5f + lbmx * (fi[1] - fkb + 1.f)) < t1) &
               (__builtin_amdgcn_exp2f(37.5f + lbmx * (fi[2] - fkb + 1.f)) < t2) &
               (__builtin_amdgcn_exp2f(37.5f + lbmx * (fi[3] - fkb + 1.f)) < t3);
      if (lane == 0) exitflag[wid] = __all(ok) ? 1 : 0;
    }
    asm volatile("s_waitcnt vmcnt(0)" ::: "memory");  // next K tile + lb landed
    __syncthreads();                                  // single barrier per tile
    if (dotest && (exitflag[0] & exitflag[1] & exitflag[2] & exitflag[3])) break;
#pragma unroll
    for (int nf = 0; nf < 4; nf++) lbj[nf] = lbn[nf];
    cur ^= 1;
  }
  asm volatile("s_waitcnt vmcnt(0)" ::: "memory");
#pragma unroll
  for (int off = 8; off >= 1; off >>= 1)
#pragma unroll
    for (int r = 0; r < 4; r++) rs[r] += __shfl_xor(rs[r], off);
  float inv[4];
#pragma unroll
  for (int r = 0; r < 4; r++) inv[r] = 1.f / rs[r];
#pragma unroll
  for (int nc = 0; nc < 8; nc++)
#pragma unroll
    for (int r = 0; r < 4; r++)
      O[(size_t)(qb + lg * 4 + r) * 2048 + h * DH + nc * 16 + lr] = f2bfc(o[nc][r] * inv[r]);
}

extern "C" void kernel_launch(void* const* d_in, const int* in_sizes, int n_in,
                              void* d_out, int out_size, void* d_ws, size_t ws_size,
                              hipStream_t stream) {
  const float* hidden = (const float*)d_in[0];
  const float* Wq     = (const float*)d_in[1];
  const float* Wk     = (const float*)d_in[2];
  const float* Wv     = (const float*)d_in[3];
  const float* Wo     = (const float*)d_in[4];
  const float* qw     = (const float*)d_in[5];
  const float* kw     = (const float*)d_in[6];
  const float* gw     = (const float*)d_in[7];
  const float* gb     = (const float*)d_in[8];
  const float* cosT   = (const float*)d_in[9];
  const float* sinT   = (const float*)d_in[10];

  char* ws = (char*)d_ws;
  const size_t MB = (size_t)1 << 20;
  unsigned short* hbf   = (unsigned short*)(ws);              // 8 MB  bf16 hidden [2048][2048]
  unsigned short* BtQKV = (unsigned short*)(ws + 8 * MB);     // 16 MB bf16 [4096][2048]
  unsigned short* WoT   = (unsigned short*)(ws + 24 * MB);    // 8 MB  bf16 [2048][2048] Wo^T
  unsigned short* Qb    = (unsigned short*)(ws + 32 * MB);    // 8 MB  bf16 [2048][2048]
  unsigned short* Kbuf  = (unsigned short*)(ws + 40 * MB);    // 4 MB  bf16 [2048][1024]
  unsigned short* Vt    = (unsigned short*)(ws + 44 * MB);    // 4 MB  bf16 [8][128][2048]
  unsigned short* AO    = (unsigned short*)(ws + 48 * MB);    // 8 MB  bf16 [2048][2048]
  float*          lbuf  = (float*)(ws + 56 * MB);             // 64 KB fp32 [8][2048]

  k_pre<<<3584, 256, 0, stream>>>(hidden, gw, gb, Wq, Wk, Wv, Wo, lbuf, hbf, BtQKV, WoT);
  k_qkv<<<512, 256, 0, stream>>>(hbf, BtQKV, qw, kw, cosT, sinT, Qb, Kbuf, Vt);
  k_attn<<<512, 256, 0, stream>>>(Qb, Kbuf, Vt, lbuf, AO);
  k_gemm_o<<<512, 256, 0, stream>>>(AO, WoT, (float*)d_out);
}

// Round 14
// 138.453 us; speedup vs baseline: 1.1972x; 1.1972x over previous
//
#include <hip/hip_runtime.h>

// ---- constants (problem sizes fixed by reference) ----
#define T_SEQ 2048
#define HID   2048
#define HQ    16
#define HKV   8
#define DH    128
#define NQKV  4096   // HQ*DH + 2*HKV*DH

#define QSCALE (0.08838834764831845f * 1.4426950408889634f)  // 1/sqrt(128) * log2(e)

typedef __attribute__((ext_vector_type(8))) __bf16 bf16x8;
typedef __attribute__((ext_vector_type(4))) float f32x4;
typedef __attribute__((ext_vector_type(8))) unsigned short ushort8;

__device__ __forceinline__ unsigned short f2bfc(float f) {
  return __builtin_bit_cast(unsigned short, (__bf16)f);
}

__device__ __forceinline__ void gload_lds16(const void* g, void* l) {
  __builtin_amdgcn_global_load_lds((const __attribute__((address_space(1))) void*)g,
                                   (__attribute__((address_space(3))) void*)l, 16, 0, 0);
}

// ---- merged pre-pass (NO atomics): blocks 0..511 = gate + fp32->bf16 hidden cvt;
//      blocks 512..3583 = weight transposes (fp32 [R][C] -> bf16 [C][R]) ----
__global__ __launch_bounds__(256) void k_pre(const float* __restrict__ hid,
                                             const float* __restrict__ gw,
                                             const float* __restrict__ gb,
                                             const float* __restrict__ Wq,
                                             const float* __restrict__ Wk,
                                             const float* __restrict__ Wv,
                                             const float* __restrict__ Wo,
                                             float* __restrict__ lb,
                                             unsigned short* __restrict__ hbf,
                                             unsigned short* __restrict__ BtQKV,
                                             unsigned short* __restrict__ WoT) {
  __shared__ float tile[64][65];
  if (blockIdx.x < 512) {
    const int t = blockIdx.x * 4 + (threadIdx.x >> 6);
    const int lane = threadIdx.x & 63;
    float acc[8];
#pragma unroll
    for (int h = 0; h < 8; h++) acc[h] = 0.f;
    const float* hrow = hid + (size_t)t * HID;
    unsigned short* brow = hbf + (size_t)t * HID;
    for (int i = lane * 4; i < HID; i += 256) {
      const float4 hv = *(const float4*)(hrow + i);
      unsigned long long pk = (unsigned long long)f2bfc(hv.x)
                            | ((unsigned long long)f2bfc(hv.y) << 16)
                            | ((unsigned long long)f2bfc(hv.z) << 32)
                            | ((unsigned long long)f2bfc(hv.w) << 48);
      *(unsigned long long*)(brow + i) = pk;
      const float ve[4] = {hv.x, hv.y, hv.z, hv.w};
#pragma unroll
      for (int e = 0; e < 4; e++) {
        const float v = ve[e];
        const float4 a = *(const float4*)(gw + (size_t)(i + e) * 8);
        const float4 b = *(const float4*)(gw + (size_t)(i + e) * 8 + 4);
        acc[0] += v * a.x; acc[1] += v * a.y; acc[2] += v * a.z; acc[3] += v * a.w;
        acc[4] += v * b.x; acc[5] += v * b.y; acc[6] += v * b.z; acc[7] += v * b.w;
      }
    }
#pragma unroll
    for (int off = 32; off >= 1; off >>= 1)
#pragma unroll
      for (int h = 0; h < 8; h++) acc[h] += __shfl_xor(acc[h], off);
    if (lane == 0) {
#pragma unroll
      for (int h = 0; h < 8; h++) {
        const float x = acc[h] + gb[h];
        const float beta = 1.f / (1.f + __expf(-x));
        lb[(size_t)h * T_SEQ + t] = log2f(fmaxf(beta, 1e-8f));   // log2 domain
      }
    }
    return;
  }
  int b = blockIdx.x - 512;
  const float* in; unsigned short* out; int ldin;
  if (b < 1024)      { in = Wq; out = BtQKV;                          ldin = 2048; }
  else if (b < 1536) { b -= 1024; in = Wk; out = BtQKV + (size_t)2048 * 2048; ldin = 1024; }
  else if (b < 2048) { b -= 1536; in = Wv; out = BtQKV + (size_t)3072 * 2048; ldin = 1024; }
  else               { b -= 2048; in = Wo; out = WoT;                 ldin = 2048; }
  const int ldout = 2048;
  const int r0 = (b & 31) * 64, c0 = (b >> 5) * 64;
  const int tid = threadIdx.x;
  {
    const int row = tid >> 4;
    const int cf  = (tid & 15) * 4;
#pragma unroll
    for (int k = 0; k < 4; k++) {
      const int r = row + k * 16;
      float4 v = *(const float4*)(in + (size_t)(r0 + r) * ldin + c0 + cf);
      tile[r][cf + 0] = v.x; tile[r][cf + 1] = v.y;
      tile[r][cf + 2] = v.z; tile[r][cf + 3] = v.w;
    }
  }
  __syncthreads();
  {
    const int c    = tid >> 3;
    const int rseg = (tid & 7) * 8;
#pragma unroll
    for (int k = 0; k < 2; k++) {
      const int cc = c + k * 32;
      ushort8 ov;
#pragma unroll
      for (int e = 0; e < 8; e++) ov[e] = f2bfc(tile[rseg + e][cc]);
      *(ushort8*)(out + (size_t)(c0 + cc) * ldout + r0 + rseg) = ov;
    }
  }
}

// ---- fused QKV GEMM + per-head RMSNorm + RoPE + Q-scale + V-transpose ----
__global__ __launch_bounds__(256) void k_qkv(const unsigned short* __restrict__ A,
                                             const unsigned short* __restrict__ Bt,
                                             const float* __restrict__ qw,
                                             const float* __restrict__ kw,
                                             const float* __restrict__ cosT,
                                             const float* __restrict__ sinT,
                                             unsigned short* __restrict__ Qb,
                                             unsigned short* __restrict__ Kb,
                                             unsigned short* __restrict__ Vt) {
  __shared__ __align__(16) char smem[67072];
  unsigned short* lA = (unsigned short*)smem;                 // 2 bufs x 8192 shorts
  unsigned short* lB = (unsigned short*)(smem + 32768);       // 2 bufs x 8192 shorts
  float* yLds  = (float*)smem;                                // [128][129] (union)
  float* ssLds = (float*)(smem + 66048);                      // [2][128]

  const int K = HID;
  const int tid = threadIdx.x;
  const int wid = tid >> 6, lane = tid & 63;
  const int lr = lane & 15, lg = lane >> 4;
  const int wr = wid >> 1, wc = wid & 1;

  int wg = blockIdx.x;
  wg = (wg & 7) * 64 + (wg >> 3);          // XCD-chunked bijective swizzle (grid 512)
  const int mt = wg & 15, nt0 = wg >> 4;   // nt0 0..31: Q heads 0..15, K 16..23, V 24..31
  const size_t tile_m = (size_t)mt * 128, tile_n = (size_t)nt0 * 128;

  f32x4 acc[4][4];
#pragma unroll
  for (int i = 0; i < 4; i++)
#pragma unroll
    for (int j = 0; j < 4; j++) acc[i][j] = (f32x4){0.f, 0.f, 0.f, 0.f};

  const int srow = lane >> 3, schunk = lane & 7;
  auto stage = [&](int kb, int buf) {
#pragma unroll
    for (int i = 0; i < 4; i++) {
      const int rbase = wid * 32 + i * 8;
      const int r = rbase + srow;
      const int cs = (schunk ^ (r & 7)) * 8;
      gload_lds16(A  + (tile_m + r) * (size_t)K + kb + cs, lA + buf * 8192 + rbase * 64);
      gload_lds16(Bt + (tile_n + r) * (size_t)K + kb + cs, lB + buf * 8192 + rbase * 64);
    }
  };

  const int nk = K / 64;
  stage(0, 0);
  int cur = 0;
  for (int t = 0; t < nk; ++t) {
    if (t + 1 < nk) {
      stage((t + 1) * 64, cur ^ 1);
      asm volatile("s_waitcnt vmcnt(8)" ::: "memory");  // tile t landed; t+1 in flight
    } else {
      asm volatile("s_waitcnt vmcnt(0)" ::: "memory");
    }
    __builtin_amdgcn_s_barrier();
#pragma unroll
    for (int kk = 0; kk < 2; kk++) {
      bf16x8 af[4], bfr[4];
#pragma unroll
      for (int mi = 0; mi < 4; mi++) {
        const int rr = wr * 64 + mi * 16 + lr;
        af[mi] = *(const bf16x8*)&lA[cur * 8192 + rr * 64 + (((kk * 4 + lg) ^ (rr & 7)) * 8)];
      }
#pragma unroll
      for (int ni = 0; ni < 4; ni++) {
        const int rr = wc * 64 + ni * 16 + lr;
        bfr[ni] = *(const bf16x8*)&lB[cur * 8192 + rr * 64 + (((kk * 4 + lg) ^ (rr & 7)) * 8)];
      }
#pragma unroll
      for (int mi = 0; mi < 4; mi++)
#pragma unroll
        for (int ni = 0; ni < 4; ni++)
          acc[mi][ni] = __builtin_amdgcn_mfma_f32_16x16x32_bf16(af[mi], bfr[ni], acc[mi][ni], 0, 0, 0);
    }
    __builtin_amdgcn_s_barrier();
    cur ^= 1;
  }

  // ================= fused epilogue =================
  const int isV = nt0 >= 24;
  const int isQ = nt0 < 16;
  float rinv[4][4];
  float wv[4];
  if (!isV) {
#pragma unroll
    for (int mi = 0; mi < 4; mi++)
#pragma unroll
      for (int r = 0; r < 4; r++) {
        float s = 0.f;
#pragma unroll
        for (int ni = 0; ni < 4; ni++) { const float v = acc[mi][ni][r]; s += v * v; }
#pragma unroll
        for (int off = 8; off >= 1; off >>= 1) s += __shfl_xor(s, off);
        if (lr == 0) ssLds[wc * 128 + wr * 64 + mi * 16 + lg * 4 + r] = s;
      }
    __syncthreads();
#pragma unroll
    for (int mi = 0; mi < 4; mi++)
#pragma unroll
      for (int r = 0; r < 4; r++) {
        const int row = wr * 64 + mi * 16 + lg * 4 + r;
        rinv[mi][r] = rsqrtf((ssLds[row] + ssLds[128 + row]) * (1.f / 128.f) + 1e-6f);
      }
    const float* w = isQ ? qw : kw;
#pragma unroll
    for (int ni = 0; ni < 4; ni++) wv[ni] = w[wc * 64 + ni * 16 + lr];
  }
#pragma unroll
  for (int mi = 0; mi < 4; mi++)
#pragma unroll
    for (int ni = 0; ni < 4; ni++)
#pragma unroll
      for (int r = 0; r < 4; r++) {
        const int row = wr * 64 + mi * 16 + lg * 4 + r;
        const int col = wc * 64 + ni * 16 + lr;
        float y = acc[mi][ni][r];
        if (!isV) y *= rinv[mi][r] * wv[ni];
        yLds[row * 129 + col] = y;
      }
  __syncthreads();
  if (!isV) {
    const float scale = isQ ? QSCALE : 1.f;
    const int row = tid >> 1, half = tid & 1;
    const int t = (int)tile_m + row;
    const float sgn = half ? 1.f : -1.f;
    const float* cro = cosT + (size_t)t * DH + half * 64;
    const float* sro = sinT + (size_t)t * DH + half * 64;
    const float* own = yLds + row * 129 + half * 64;
    const float* par = yLds + row * 129 + (half ^ 1) * 64;
    unsigned short* op = isQ ? (Qb + (size_t)t * 2048 + nt0 * DH + half * 64)
                             : (Kb + (size_t)t * 1024 + (nt0 - 16) * DH + half * 64);
#pragma unroll
    for (int c = 0; c < 64; c += 8) {
      ushort8 ov;
#pragma unroll
      for (int e = 0; e < 8; e++)
        ov[e] = f2bfc((own[c + e] * cro[c + e] + sgn * par[c + e] * sro[c + e]) * scale);
      *(ushort8*)(op + c) = ov;
    }
  } else {
    const int d = tid >> 1, thalf = tid & 1;
    const int vh = nt0 - 24;
    unsigned short* op = Vt + (size_t)(vh * DH + d) * T_SEQ + tile_m + thalf * 64;
#pragma unroll
    for (int s = 0; s < 64; s += 8) {
      ushort8 ov;
#pragma unroll
      for (int e = 0; e < 8; e++) ov[e] = f2bfc(yLds[(thalf * 64 + s + e) * 129 + d]);
      *(ushort8*)(op + s) = ov;
    }
  }
}

// ---- out-proj GEMM: 64x128 tiles, grid 512 (2 blocks/CU), depth-2 pipeline
//      (3 LDS bufs, counted vmcnt never drained in-loop), plain fp32 stores ----
__global__ __launch_bounds__(256) void k_gemm_o(const unsigned short* __restrict__ A,
                                                const unsigned short* __restrict__ Bt,
                                                float* __restrict__ C) {
  __shared__ unsigned short lA[3][64 * 64];    // 24 KB
  __shared__ unsigned short lB[3][128 * 64];   // 48 KB (72 KB total; 2 blocks/CU)
  const int K = 2048, N = 2048;
  const int tid = threadIdx.x;
  const int wid = tid >> 6, lane = tid & 63;
  const int lr = lane & 15, lg = lane >> 4;
  const int wr = wid >> 1, wc = wid & 1;

  int wg = blockIdx.x;
  wg = (wg & 7) * 64 + (wg >> 3);          // XCD-chunked bijective swizzle (grid 512)
  const size_t tile_m = (size_t)(wg & 31) * 64;    // 32 M-tiles
  const size_t tile_n = (size_t)(wg >> 5) * 128;   // 16 N-tiles

  f32x4 acc[2][4];
#pragma unroll
  for (int i = 0; i < 2; i++)
#pragma unroll
    for (int j = 0; j < 4; j++) acc[i][j] = (f32x4){0.f, 0.f, 0.f, 0.f};

  const int srow = (lane >> 3);
  const int schunk = lane & 7;
  auto stage = [&](int kb, int buf) {
#pragma unroll
    for (int i = 0; i < 2; i++) {            // A: 64 rows
      const int rbase = wid * 16 + i * 8;
      const int r = rbase + srow;
      const int cs = (schunk ^ (r & 7)) * 8;
      gload_lds16(A + (tile_m + r) * (size_t)K + kb + cs, &lA[buf][rbase * 64]);
    }
#pragma unroll
    for (int i = 0; i < 4; i++) {            // B: 128 rows
      const int rbase = wid * 32 + i * 8;
      const int r = rbase + srow;
      const int cs = (schunk ^ (r & 7)) * 8;
      gload_lds16(Bt + (tile_n + r) * (size_t)K + kb + cs, &lB[buf][rbase * 64]);
    }
  };

  const int nk = K / 64;   // 32
  stage(0, 0);
  stage(64, 1);
  int cur = 0;
  for (int t = 0; t < nk; ++t) {
    if (t + 2 < nk) {
      int nb = cur + 2; if (nb >= 3) nb -= 3;
      stage((t + 2) * 64, nb);
      asm volatile("s_waitcnt vmcnt(12)" ::: "memory");  // tile t landed; t+1,t+2 in flight
    } else if (t + 2 == nk) {
      asm volatile("s_waitcnt vmcnt(6)" ::: "memory");   // tile t landed; t+1 in flight
    } else {
      asm volatile("s_waitcnt vmcnt(0)" ::: "memory");
    }
    __builtin_amdgcn_s_barrier();
#pragma unroll
    for (int kk = 0; kk < 2; kk++) {
      bf16x8 af[2], bfr[4];
#pragma unroll
      for (int mi = 0; mi < 2; mi++) {
        const int rr = wr * 32 + mi * 16 + lr;
        af[mi] = *(const bf16x8*)&lA[cur][rr * 64 + (((kk * 4 + lg) ^ (rr & 7)) * 8)];
      }
#pragma unroll
      for (int ni = 0; ni < 4; ni++) {
        const int rr = wc * 64 + ni * 16 + lr;
        bfr[ni] = *(const bf16x8*)&lB[cur][rr * 64 + (((kk * 4 + lg) ^ (rr & 7)) * 8)];
      }
#pragma unroll
      for (int mi = 0; mi < 2; mi++)
#pragma unroll
        for (int ni = 0; ni < 4; ni++)
          acc[mi][ni] = __builtin_amdgcn_mfma_f32_16x16x32_bf16(af[mi], bfr[ni], acc[mi][ni], 0, 0, 0);
    }
    __builtin_amdgcn_s_barrier();   // all waves done with cur before it is restaged
    cur = (cur + 1 == 3) ? 0 : cur + 1;
  }
#pragma unroll
  for (int mi = 0; mi < 2; mi++)
#pragma unroll
    for (int ni = 0; ni < 4; ni++)
#pragma unroll
      for (int r = 0; r < 4; r++) {
        const size_t idx = (tile_m + wr * 32 + mi * 16 + lg * 4 + r) * (size_t)N +
                           tile_n + wc * 64 + ni * 16 + lr;
        C[idx] = acc[mi][ni][r];
      }
}

// ---- flash attention: reverse iteration, fixed-max exp2 softmax, rigorous early exit;
//      K AND V DMA-staged to LDS (dbuf); inline lbmax; setprio on MFMA (round-12 struct) ----
__global__ __launch_bounds__(256, 2) void k_attn(const unsigned short* __restrict__ Q,
                                                 const unsigned short* __restrict__ Kb,
                                                 const unsigned short* __restrict__ Vt,
                                                 const float* __restrict__ lb,
                                                 unsigned short* __restrict__ O) {
  const int tid = threadIdx.x;
  const int wid = tid >> 6, lane = tid & 63;
  const int lr = lane & 15, lg = lane >> 4;
  const int u = blockIdx.x;
  const int h = u & 15;
  const int qp = (u >> 4) & 15;
  const int qblk = (u >> 8) ? (31 - qp) : qp;
  const int kvh = h >> 1;
  const int qb = qblk * 64 + wid * 16;

  __shared__ __align__(16) unsigned short lK[2][64 * 128];
  __shared__ __align__(16) unsigned short lV[2][128 * 64];
  __shared__ __align__(16) unsigned short plds[4][16 * 72];
  __shared__ int exitflag[4];
  __shared__ float sred[4];

  const float* lbh = lb + (size_t)kvh * T_SEQ;
  const unsigned short* Kh = Kb + kvh * DH;
  const unsigned short* Vh = Vt + (size_t)kvh * DH * T_SEQ;
  unsigned short* myp = plds[wid];

  bf16x8 qf[4];
  {
    const unsigned short* Qp = Q + (size_t)(qb + lr) * 2048 + h * DH + lg * 8;
#pragma unroll
    for (int kc = 0; kc < 4; kc++) qf[kc] = *(const bf16x8*)(Qp + kc * 32);
  }

  f32x4 o[8];
#pragma unroll
  for (int nc = 0; nc < 8; nc++) o[nc] = (f32x4){0.f, 0.f, 0.f, 0.f};
  float rs[4] = {0.f, 0.f, 0.f, 0.f};

  const int ir[4] = {qb + lg * 4, qb + lg * 4 + 1, qb + lg * 4 + 2, qb + lg * 4 + 3};
  const float fi[4] = {(float)ir[0], (float)ir[1], (float)ir[2], (float)ir[3]};

  auto stage = [&](int kb, int buf) {
#pragma unroll
    for (int q = 0; q < 4; q++) {
      const int t = wid * 4 + q;
      {
        const int r = 4 * t + (lane >> 4);
        const int j = (lane & 15) ^ (r & 7);
        gload_lds16(Kh + (size_t)(kb + r) * 1024 + j * 8, &lK[buf][t * 512]);
      }
      {
        const int r = 8 * t + (lane >> 3);
        const int j = (lane & 7) ^ (r & 7);
        gload_lds16(Vh + (size_t)r * 2048 + kb + j * 8, &lV[buf][t * 512]);
      }
    }
  };

  const int nt = qblk + 1;
  int cur = 0;
  float lbj[4], lbn[4];
  {
    const int kb0 = (nt - 1) * 64;
    stage(kb0, 0);
#pragma unroll
    for (int nf = 0; nf < 4; nf++) lbj[nf] = lbh[kb0 + nf * 16 + lr];
  }
  // inline per-head lbmax (lb row is L2-hot)
  {
    float v = -1e30f;
    for (int i = tid; i < T_SEQ; i += 256) v = fmaxf(v, lbh[i]);
#pragma unroll
    for (int off = 32; off >= 1; off >>= 1) v = fmaxf(v, __shfl_xor(v, off));
    if (lane == 0) sred[wid] = v;
  }
  asm volatile("s_waitcnt vmcnt(0)" ::: "memory");
  __syncthreads();
  const float lbmx = fmaxf(fmaxf(sred[0], sred[1]), fmaxf(sred[2], sred[3]));

  for (int kt = nt - 1; kt >= 0; --kt) {
    const int kb = kt * 64;
    if (kt > 0) {
      stage(kb - 64, cur ^ 1);
#pragma unroll
      for (int nf = 0; nf < 4; nf++) lbn[nf] = lbh[kb - 64 + nf * 16 + lr];
    }
    f32x4 sfr[4];
    __builtin_amdgcn_s_setprio(1);
#pragma unroll
    for (int nf = 0; nf < 4; nf++) {
      const int rr = nf * 16 + lr;
      const unsigned short* kbase = &lK[cur][rr * 128];
      f32x4 a = (f32x4){0.f, 0.f, 0.f, 0.f};
#pragma unroll
      for (int kc = 0; kc < 4; kc++) {
        const bf16x8 kf = *(const bf16x8*)&kbase[((kc * 4 + lg) ^ (rr & 7)) * 8];
        a = __builtin_amdgcn_mfma_f32_16x16x32_bf16(qf[kc], kf, a, 0, 0, 0);
      }
      sfr[nf] = a;
    }
    __builtin_amdgcn_s_setprio(0);
    const int last = (kt == nt - 1);
#pragma unroll
    for (int nf = 0; nf < 4; nf++) {
      const int j = kb + nf * 16 + lr;
      const float fj = (float)j;
#pragma unroll
      for (int r = 0; r < 4; r++) {
        float sv = sfr[nf][r] + lbj[nf] * (fi[r] - fj);
        if (last) sv = (j <= ir[r]) ? sv : -1e30f;
        const float p = __builtin_amdgcn_exp2f(sv);
        sfr[nf][r] = p;
        rs[r] += p;
      }
    }
#pragma unroll
    for (int nf = 0; nf < 4; nf++)
#pragma unroll
      for (int r = 0; r < 4; r++)
        myp[(lg * 4 + r) * 72 + nf * 16 + lr] = f2bfc(sfr[nf][r]);
    const bf16x8 pa0 = *(const bf16x8*)&myp[lr * 72 + lg * 8];
    const bf16x8 pa1 = *(const bf16x8*)&myp[lr * 72 + 32 + lg * 8];
    __builtin_amdgcn_s_setprio(1);
#pragma unroll
    for (int nc = 0; nc < 8; nc++) {
      const int rr = nc * 16 + lr;
      const unsigned short* vbase = &lV[cur][rr * 64];
      const bf16x8 v0 = *(const bf16x8*)&vbase[(lg ^ (rr & 7)) * 8];
      const bf16x8 v1 = *(const bf16x8*)&vbase[((4 + lg) ^ (rr & 7)) * 8];
      o[nc] = __builtin_amdgcn_mfma_f32_16x16x32_bf16(pa0, v0, o[nc], 0, 0, 0);
      o[nc] = __builtin_amdgcn_mfma_f32_16x16x32_bf16(pa1, v1, o[nc], 0, 0, 0);
    }
    __builtin_amdgcn_s_setprio(0);
    // rigorous early exit: tail(row i) <= 2048*2^(16.5+lbmx*(i-kb+1)) < 2^-10 * lsum
    const int dotest = ((kt & 1) == 0) && (kt > 0);
    if (dotest) {
      float t0 = rs[0], t1 = rs[1], t2 = rs[2], t3 = rs[3];
#pragma unroll
      for (int off = 8; off >= 1; off >>= 1) {
        t0 += __shfl_xor(t0, off); t1 += __shfl_xor(t1, off);
        t2 += __shfl_xor(t2, off); t3 += __shfl_xor(t3, off);
      }
      const float fkb = (float)kb;
      int ok = (__builtin_amdgcn_exp2f(37.5f + lbmx * (fi[0] - fkb + 1.f)) < t0) &
               (__builtin_amdgcn_exp2f(37.5f + lbmx * (fi[1] - fkb + 1.f)) < t1) &
               (__builtin_amdgcn_exp2f(37.5f + lbmx * (fi[2] - fkb + 1.f)) < t2) &
               (__builtin_amdgcn_exp2f(37.5f + lbmx * (fi[3] - fkb + 1.f)) < t3);
      if (lane == 0) exitflag[wid] = __all(ok) ? 1 : 0;
    }
    asm volatile("s_waitcnt vmcnt(0)" ::: "memory");
    __syncthreads();
    if (dotest && (exitflag[0] & exitflag[1] & exitflag[2] & exitflag[3])) break;
#pragma unroll
    for (int nf = 0; nf < 4; nf++) lbj[nf] = lbn[nf];
    cur ^= 1;
  }
  asm volatile("s_waitcnt vmcnt(0)" ::: "memory");
#pragma unroll
  for (int off = 8; off >= 1; off >>= 1)
#pragma unroll
    for (int r = 0; r < 4; r++) rs[r] += __shfl_xor(rs[r], off);
  float inv[4];
#pragma unroll
  for (int r = 0; r < 4; r++) inv[r] = 1.f / rs[r];
#pragma unroll
  for (int nc = 0; nc < 8; nc++)
#pragma unroll
    for (int r = 0; r < 4; r++)
      O[(size_t)(qb + lg * 4 + r) * 2048 + h * DH + nc * 16 + lr] = f2bfc(o[nc][r] * inv[r]);
}

extern "C" void kernel_launch(void* const* d_in, const int* in_sizes, int n_in,
                              void* d_out, int out_size, void* d_ws, size_t ws_size,
                              hipStream_t stream) {
  const float* hidden = (const float*)d_in[0];
  const float* Wq     = (const float*)d_in[1];
  const float* Wk     = (const float*)d_in[2];
  const float* Wv     = (const float*)d_in[3];
  const float* Wo     = (const float*)d_in[4];
  const float* qw     = (const float*)d_in[5];
  const float* kw     = (const float*)d_in[6];
  const float* gw     = (const float*)d_in[7];
  const float* gb     = (const float*)d_in[8];
  const float* cosT   = (const float*)d_in[9];
  const float* sinT   = (const float*)d_in[10];

  char* ws = (char*)d_ws;
  const size_t MB = (size_t)1 << 20;
  unsigned short* hbf   = (unsigned short*)(ws);              // 8 MB  bf16 hidden [2048][2048]
  unsigned short* BtQKV = (unsigned short*)(ws + 8 * MB);     // 16 MB bf16 [4096][2048]
  unsigned short* WoT   = (unsigned short*)(ws + 24 * MB);    // 8 MB  bf16 [2048][2048] Wo^T
  unsigned short* Qb    = (unsigned short*)(ws + 32 * MB);    // 8 MB  bf16 [2048][2048]
  unsigned short* Kbuf  = (unsigned short*)(ws + 40 * MB);    // 4 MB  bf16 [2048][1024]
  unsigned short* Vt    = (unsigned short*)(ws + 44 * MB);    // 4 MB  bf16 [8][128][2048]
  unsigned short* AO    = (unsigned short*)(ws + 48 * MB);    // 8 MB  bf16 [2048][2048]
  float*          lbuf  = (float*)(ws + 56 * MB);             // 64 KB fp32 [8][2048]

  k_pre<<<3584, 256, 0, stream>>>(hidden, gw, gb, Wq, Wk, Wv, Wo, lbuf, hbf, BtQKV, WoT);
  k_qkv<<<512, 256, 0, stream>>>(hbf, BtQKV, qw, kw, cosT, sinT, Qb, Kbuf, Vt);
  k_attn<<<512, 256, 0, stream>>>(Qb, Kbuf, Vt, lbuf, AO);
  k_gemm_o<<<512, 256, 0, stream>>>(AO, WoT, (float*)d_out);
}